// Round 10
// baseline (589.292 us; speedup 1.0000x reference)
//
#include <hip/hip_runtime.h>

typedef unsigned int uint;
typedef unsigned short ushort;
typedef __attribute__((ext_vector_type(8))) short short8;  // 8 bf16 = 4 VGPR
typedef __attribute__((ext_vector_type(4))) float f32x4;

#define NPOS 16384
#define PLANE 2097152
// LDS: ONLY the H double-buffer (cross-wave broadcast). 2 x [hi 4KB | lo 4KB].
// X / gate / old-out live in per-lane registers, 4-slot rotation, prefetch
// distance 3, loads issued at the TOP of each body (before MFMAs and stores,
// so waits for loads never queue behind stores in the vmcnt FIFO).
#define LDS_BYTES 16384

template <int N> struct IC { static constexpr int value = N; };

__device__ __forceinline__ uint fbits(float a) { return __builtin_bit_cast(uint, a); }
__device__ __forceinline__ uint rnehi(float a) {  // RNE bf16 high split
  const uint u = fbits(a);
  return (u + 0x7FFFu + ((u >> 16) & 1u)) & 0xFFFF0000u;
}
__device__ __forceinline__ float fhi(float a) { return __builtin_bit_cast(float, rnehi(a)); }
__device__ __forceinline__ uint packhi(float a, float b) { return (rnehi(a) >> 16) | rnehi(b); }
__device__ __forceinline__ uint packtr(float a, float b) {
  return (fbits(a) >> 16) | (fbits(b) & 0xFFFF0000u);
}
__device__ __forceinline__ float b2f(uint h16) { return __builtin_bit_cast(float, h16 << 16); }

__device__ __forceinline__ f32x4 MF(short8 a, short8 b, f32x4 c) {
  return __builtin_amdgcn_mfma_f32_16x16x32_bf16(a, b, c, 0, 0, 0);
}
__device__ __forceinline__ void split8(float4 v0, float4 v1, short8& hi, short8& lo) {
  union { short8 s; uint u[4]; } H, L;
  H.u[0] = packhi(v0.x, v0.y); H.u[1] = packhi(v0.z, v0.w);
  H.u[2] = packhi(v1.x, v1.y); H.u[3] = packhi(v1.z, v1.w);
  L.u[0] = packtr(v0.x - fhi(v0.x), v0.y - fhi(v0.y));
  L.u[1] = packtr(v0.z - fhi(v0.z), v0.w - fhi(v0.w));
  L.u[2] = packtr(v1.x - fhi(v1.x), v1.y - fhi(v1.y));
  L.u[3] = packtr(v1.z - fhi(v1.z), v1.w - fhi(v1.w));
  hi = H.s; lo = L.s;
}

#define BAR() asm volatile("s_waitcnt lgkmcnt(0)\n\ts_barrier" ::: "memory")

__global__ __launch_bounds__(256) void k_transpose_x(const float* __restrict__ x,
                                                     ushort* __restrict__ xhi,
                                                     ushort* __restrict__ xlo) {
  __shared__ float tile[128][129];
  const int b = blockIdx.x >> 7, h = blockIdx.x & 127;
  const int t = threadIdx.x, half = t >> 7, lane = t & 127;
  const float* src = x + (size_t)b * PLANE + (size_t)h * 128;  // [c][w]
  for (int c0 = 0; c0 < 128; c0 += 2) {
    const int c = c0 + half;
    tile[c][lane] = src[(size_t)c * NPOS + lane];
  }
  __syncthreads();
  const int wq = t >> 6, cp = t & 63;
  for (int w0 = 0; w0 < 128; w0 += 4) {
    const int w = w0 + wq;
    const float v0 = tile[2 * cp][w], v1 = tile[2 * cp + 1][w];
    const size_t e = ((size_t)(b * 128 + w) * 128 + h) * 128 + 2 * cp;
    *(uint*)(xhi + e) = packhi(v0, v1);
    *(uint*)(xlo + e) = packtr(v0 - fhi(v0), v1 - fhi(v1));
  }
}

__global__ __launch_bounds__(256) void k_transpose_y(const float* __restrict__ y,
                                                     float* __restrict__ yt1,
                                                     float* __restrict__ yt2) {
  __shared__ float tile[128][129];
  const int b = blockIdx.x >> 7, h = blockIdx.x & 127;
  const int t = threadIdx.x, half = t >> 7, lane = t & 127;
  const float* src = y + (size_t)b * PLANE + (size_t)h * 128;
  for (int c0 = 0; c0 < 128; c0 += 2) {
    const int c = c0 + half;
    tile[c][lane] = src[(size_t)c * NPOS + lane];
  }
  __syncthreads();
  float* d1 = yt1 + (size_t)b * PLANE + (size_t)h * 128;
  float* d2 = yt2 + ((size_t)(b * 128 + h)) * NPOS;
  for (int w0 = 0; w0 < 128; w0 += 2) {
    const int w = w0 + half;
    const float v = tile[lane][w];
    d1[(size_t)w * NPOS + lane] = v;
    d2[(size_t)w * 128 + lane] = v;
  }
}

// ---------------------------------------------------------------------------
// 16-line batched gated scan. 4 waves; wave wv owns out rows [32wv,32wv+32).
// Lane l: line=l&15 (MFMA n / gate column), g4=l>>4.
// Register streams (4-slot rotation, prefetch distance 3, loads at body top):
//   XH/XL[slot][kt] : B-fragments of input (line l&15, k=32kt+8g4..+8)
//   GV[slot][tt]    : gate float4 (step s uses y[P(s-1)])
//   OV[slot][tt]    : prior output for ACCUM RMW at pos P(s)
// LDS: only H dbuf (hi/lo planes, fragment-linear [chunk][line]x16B).
// Slot r = s&3, H write buffer = s&1 -- all static via 4-body unroll.
// ---------------------------------------------------------------------------
template <bool RELU0, bool REV, bool ACCUM, bool OUT16>
__device__ __forceinline__ void scan16(
    char* lds,
    const ushort* __restrict__ xhi, const ushort* __restrict__ xlo, size_t in_base,
    const float* __restrict__ gate, size_t gate_base,
    float* __restrict__ outf, ushort* __restrict__ outhi, ushort* __restrict__ outlo,
    size_t out_base, int out_ps, int out_ls,
    const float* __restrict__ Wa, const float* __restrict__ Ba,
    const float* __restrict__ Wb, const float* __restrict__ Bb) {
  const int t = threadIdx.x;
  const int wv = t >> 6, l = t & 63;
  const int line = l & 15, g4 = l >> 4;

  // resident weight fragments (A-layout: row=32wv+16tt+line, k=32kt+8g4+j)
  short8 wah[2][4], wal[2][4], wbh[2][4], wbl[2][4];
#pragma unroll
  for (int tt = 0; tt < 2; ++tt)
#pragma unroll
    for (int kt = 0; kt < 4; ++kt) {
      const int row = 32 * wv + 16 * tt + line;
      const int kc = 32 * kt + 8 * g4;
      split8(*(const float4*)(Wa + row * 128 + kc), *(const float4*)(Wa + row * 128 + kc + 4),
             wah[tt][kt], wal[tt][kt]);
      split8(*(const float4*)(Wb + row * 128 + kc), *(const float4*)(Wb + row * 128 + kc + 4),
             wbh[tt][kt], wbl[tt][kt]);
    }
  f32x4 baf[2], bbf[2];
#pragma unroll
  for (int tt = 0; tt < 2; ++tt) {
    baf[tt] = *(const f32x4*)(Ba + 32 * wv + 16 * tt + 4 * g4);
    bbf[tt] = *(const f32x4*)(Bb + 32 * wv + 16 * tt + 4 * g4);
  }

  auto P = [](int p) -> int { return REV ? 127 - p : p; };

  // per-lane stream bases
  const size_t xoff = in_base + (size_t)line * NPOS + 8 * g4;           // halfwords
  const size_t goff = gate_base + (size_t)line * NPOS + 32 * wv + 4 * g4;
  const size_t ooff = out_base + (size_t)line * out_ls + 32 * wv + 4 * g4;

  short8 XH[4][4], XL[4][4];
  f32x4 GV[4][2], OV[4][2];

  auto loadX = [&](auto SL, int pos) {
    constexpr int sl = decltype(SL)::value;
    const size_t e = xoff + (size_t)pos * 128;
#pragma unroll
    for (int kt = 0; kt < 4; ++kt) {
      XH[sl][kt] = *(const short8*)(xhi + e + 32 * kt);
      XL[sl][kt] = *(const short8*)(xlo + e + 32 * kt);
    }
  };
  auto loadG = [&](auto SL, int gpos) {
    constexpr int sl = decltype(SL)::value;
    const size_t e = goff + (size_t)gpos * 128;
    GV[sl][0] = *(const f32x4*)(gate + e);
    GV[sl][1] = *(const f32x4*)(gate + e + 16);
  };
  auto loadO = [&](auto SL, int pos) {
    constexpr int sl = decltype(SL)::value;
    const size_t e = ooff + (size_t)pos * out_ps;
    OV[sl][0] = *(const f32x4*)(outf + e);
    OV[sl][1] = *(const f32x4*)(outf + e + 16);
  };

  // ---- step 0: h0 = relu?(x[P(0)]) via per-lane C-layout loads ----
  {
    char* Hwr = lds;  // dbuf 0
#pragma unroll
    for (int tt = 0; tt < 2; ++tt) {
      const int ci0 = 32 * wv + 16 * tt + 4 * g4;
      const size_t xe = in_base + (size_t)line * NPOS + (size_t)P(0) * 128 + ci0;
      const uint2 xh = *(const uint2*)(xhi + xe);
      const uint2 xl = *(const uint2*)(xlo + xe);
      float4 f;
      f.x = b2f(xh.x & 0xFFFFu) + b2f(xl.x & 0xFFFFu);
      f.y = b2f(xh.x >> 16) + b2f(xl.x >> 16);
      f.z = b2f(xh.y & 0xFFFFu) + b2f(xl.y & 0xFFFFu);
      f.w = b2f(xh.y >> 16) + b2f(xl.y >> 16);
      if (RELU0) {
        f.x = fmaxf(f.x, 0.f); f.y = fmaxf(f.y, 0.f);
        f.z = fmaxf(f.z, 0.f); f.w = fmaxf(f.w, 0.f);
      }
      uint2 hw, lw;
      hw.x = packhi(f.x, f.y); hw.y = packhi(f.z, f.w);
      lw.x = packtr(f.x - fhi(f.x), f.y - fhi(f.y));
      lw.y = packtr(f.z - fhi(f.z), f.w - fhi(f.w));
      const int cw = 4 * wv + 2 * tt + (g4 >> 1);
      const int boff = (cw * 16 + line) * 16 + 8 * (g4 & 1);
      *(uint2*)(Hwr + boff) = hw;
      *(uint2*)(Hwr + 4096 + boff) = lw;
      const size_t oe = ooff + (size_t)P(0) * out_ps + 16 * tt;
      if (OUT16) {
        *(uint2*)(outhi + oe) = hw;
        *(uint2*)(outlo + oe) = lw;
      } else {
        float4 o = f;
        if (ACCUM) {
          const float4 ov = *(const float4*)(outf + oe);
          o.x += ov.x; o.y += ov.y; o.z += ov.z; o.w += ov.w;
        }
        *(float4*)(outf + oe) = o;
      }
    }
  }
  // preload slots 1..3 (steps 1..3); slot 0 is filled at body s=1.
  loadX(IC<1>{}, P(1)); loadG(IC<1>{}, P(0));
  loadX(IC<2>{}, P(2)); loadG(IC<2>{}, P(1));
  loadX(IC<3>{}, P(3)); loadG(IC<3>{}, P(2));
  if constexpr (ACCUM) {
    loadO(IC<1>{}, P(1)); loadO(IC<2>{}, P(2)); loadO(IC<3>{}, P(3));
  }
  BAR();

  // ---- per-step body (slot r = s&3, H buffers static from r) ----
  auto body = [&](auto R_, int s) {
    constexpr int r = decltype(R_)::value;
    constexpr int rn = (r + 3) & 3;   // landing slot for step s+3
    constexpr int hw_ = r & 1;        // H write buffer = s&1
    // TOP: prefetch for step s+3 (before MFMAs and stores -> waits on these
    // loads never queue behind stores in the vmcnt FIFO)
    {
      const int pn = (s + 3 <= 127) ? (s + 3) : 127;
      const int gn = (s + 2 <= 126) ? (s + 2) : 126;
      loadX(IC<rn>{}, P(pn));
      loadG(IC<rn>{}, P(gn));
      if constexpr (ACCUM) loadO(IC<rn>{}, P(pn));
    }
    const char* Hrd = lds + (hw_ ^ 1) * 8192;
    char* Hwr = lds + hw_ * 8192;
    const f32x4 z = {0.f, 0.f, 0.f, 0.f};
    f32x4 aFa[2] = {baf[0], baf[1]}, aFb[2] = {z, z};
    f32x4 aRa[2] = {bbf[0], bbf[1]}, aRb[2] = {z, z};
    __builtin_amdgcn_s_setprio(1);
#define KT(kt, AF, AR)                                                    \
    {                                                                     \
      const short8 hh = *(const short8*)(Hrd + kt * 1024 + l * 16);       \
      const short8 hl = *(const short8*)(Hrd + 4096 + kt * 1024 + l * 16);\
      AF[0] = MF(wah[0][kt], XH[r][kt], AF[0]);                           \
      AF[1] = MF(wah[1][kt], XH[r][kt], AF[1]);                           \
      AF[0] = MF(wah[0][kt], XL[r][kt], AF[0]);                           \
      AF[1] = MF(wah[1][kt], XL[r][kt], AF[1]);                           \
      AF[0] = MF(wal[0][kt], XH[r][kt], AF[0]);                           \
      AF[1] = MF(wal[1][kt], XH[r][kt], AF[1]);                           \
      AR[0] = MF(wbh[0][kt], hh, AR[0]);                                  \
      AR[1] = MF(wbh[1][kt], hh, AR[1]);                                  \
      AR[0] = MF(wbh[0][kt], hl, AR[0]);                                  \
      AR[1] = MF(wbh[1][kt], hl, AR[1]);                                  \
      AR[0] = MF(wbl[0][kt], hh, AR[0]);                                  \
      AR[1] = MF(wbl[1][kt], hh, AR[1]);                                  \
    }
    KT(0, aFa, aRa) KT(1, aFb, aRb) KT(2, aFa, aRa) KT(3, aFb, aRb)
#undef KT
    __builtin_amdgcn_s_setprio(0);

    const f32x4 aFv[2] = {aFa[0] + aFb[0], aFa[1] + aFb[1]};
    const f32x4 aRv[2] = {aRa[0] + aRb[0], aRa[1] + aRb[1]};
#pragma unroll
    for (int tt = 0; tt < 2; ++tt) {
      const f32x4 g = GV[r][tt];
      float4 h;
      h.x = fmaxf(fmaf(aRv[tt][0], g[0], aFv[tt][0]), 0.f);
      h.y = fmaxf(fmaf(aRv[tt][1], g[1], aFv[tt][1]), 0.f);
      h.z = fmaxf(fmaf(aRv[tt][2], g[2], aFv[tt][2]), 0.f);
      h.w = fmaxf(fmaf(aRv[tt][3], g[3], aFv[tt][3]), 0.f);
      uint2 hw2, lw2;
      hw2.x = packhi(h.x, h.y); hw2.y = packhi(h.z, h.w);
      lw2.x = packtr(h.x - fhi(h.x), h.y - fhi(h.y));
      lw2.y = packtr(h.z - fhi(h.z), h.w - fhi(h.w));
      const int cw = 4 * wv + 2 * tt + (g4 >> 1);
      const int boff = (cw * 16 + line) * 16 + 8 * (g4 & 1);
      *(uint2*)(Hwr + boff) = hw2;
      *(uint2*)(Hwr + 4096 + boff) = lw2;
      const size_t oe = ooff + (size_t)P(s) * out_ps + 16 * tt;
      if (OUT16) {
        *(uint2*)(outhi + oe) = hw2;
        *(uint2*)(outlo + oe) = lw2;
      } else {
        float4 o = h;
        if (ACCUM) {
          const f32x4 ov = OV[r][tt];
          o.x += ov[0]; o.y += ov[1]; o.z += ov[2]; o.w += ov[3];
        }
        *(float4*)(outf + oe) = o;
      }
    }
    BAR();
  };

  body(IC<1>{}, 1);
  body(IC<2>{}, 2);
  body(IC<3>{}, 3);
#pragma unroll 1
  for (int s = 4; s < 128; s += 4) {
    body(IC<0>{}, s);
    body(IC<1>{}, s + 1);
    body(IC<2>{}, s + 2);
    body(IC<3>{}, s + 3);
  }
}

// Phase 1: 64 blocks = [scan(2)][b(4)][wgrp(8)]
__global__ __launch_bounds__(256, 1) void k_scan_ph1(
    const ushort* __restrict__ xhi, const ushort* __restrict__ xlo,
    const float* __restrict__ yt1,
    ushort* __restrict__ hs_hi, ushort* __restrict__ hs_lo,
    ushort* __restrict__ hn_hi, ushort* __restrict__ hn_lo,
    const float* w1, const float* b1, const float* w2, const float* b2,
    const float* w9, const float* b9, const float* w10, const float* b10) {
  __shared__ __align__(16) char lds[LDS_BYTES];
  const int id = blockIdx.x;
  const int scan = id >> 5, b = (id >> 3) & 3, wg = id & 7;
  const size_t in_base = ((size_t)(b * 128 + wg * 16)) * NPOS;
  const size_t out_base = (size_t)b * PLANE + (size_t)(wg * 16) * 128;
  if (scan == 0)
    scan16<false, false, false, true>(lds, xhi, xlo, in_base, yt1, in_base,
                                      nullptr, hs_hi, hs_lo, out_base, NPOS, 128,
                                      w1, b1, w2, b2);
  else
    scan16<true, true, false, true>(lds, xhi, xlo, in_base, yt1, in_base,
                                    nullptr, hn_hi, hn_lo, out_base, NPOS, 128,
                                    w9, b9, w10, b10);
}

// Phase 2: 64 blocks = [grp(2)][b(4)][hgrp(8)]; grp0: SE then SW(acc) -> outA;
// grp1: NE then NW(acc) -> outB.
__global__ __launch_bounds__(256, 1) void k_scan_ph2(
    const ushort* __restrict__ hs_hi, const ushort* __restrict__ hs_lo,
    const ushort* __restrict__ hn_hi, const ushort* __restrict__ hn_lo,
    const float* __restrict__ yt2, float* __restrict__ outA, float* __restrict__ outB,
    const float* w4, const float* b4, const float* w5, const float* b5,
    const float* w7, const float* b7, const float* w8, const float* b8,
    const float* w12, const float* b12, const float* w13, const float* b13,
    const float* w15, const float* b15, const float* w16, const float* b16) {
  __shared__ __align__(16) char lds[LDS_BYTES];
  const int id = blockIdx.x;
  const int grp = id >> 5, b = (id >> 3) & 3, hg = id & 7;
  const size_t base = ((size_t)(b * 128 + hg * 16)) * NPOS;
  const ushort* ihi = grp ? hn_hi : hs_hi;
  const ushort* ilo = grp ? hn_lo : hs_lo;
  float* o = grp ? outB : outA;
  const float* wa1 = grp ? w12 : w4; const float* ba1 = grp ? b12 : b4;
  const float* wb1 = grp ? w13 : w5; const float* bb1 = grp ? b13 : b5;
  const float* wa2 = grp ? w15 : w7; const float* ba2 = grp ? b15 : b7;
  const float* wb2 = grp ? w16 : w8; const float* bb2 = grp ? b16 : b8;
  // out element [pos=w][line=h][c]: pos stride 128, line stride NPOS
  scan16<true, false, false, false>(lds, ihi, ilo, base, yt2, base,
                                    o, nullptr, nullptr, base, 128, NPOS,
                                    wa1, ba1, wb1, bb1);
  asm volatile("s_waitcnt vmcnt(0) lgkmcnt(0)\n\ts_barrier" ::: "memory");
  scan16<true, true, true, false>(lds, ihi, ilo, base, yt2, base,
                                  o, nullptr, nullptr, base, 128, NPOS,
                                  wa2, ba2, wb2, bb2);
}

// out[b][c][h][w] = outA[b][h][w][c] + outB[b][h][w][c]
__global__ __launch_bounds__(256) void k_final(const float* __restrict__ outA,
                                               const float* __restrict__ outB,
                                               float* __restrict__ out) {
  __shared__ float tile[128][129];
  const int b = blockIdx.x >> 7, h = blockIdx.x & 127;
  const int t = threadIdx.x, half = t >> 7, lane = t & 127;
  const float* pa = outA + ((size_t)(b * 128 + h)) * NPOS;
  const float* pb = outB + ((size_t)(b * 128 + h)) * NPOS;
  for (int w0 = 0; w0 < 128; w0 += 2) {
    const int w = w0 + half;
    tile[w][lane] = pa[(size_t)w * 128 + lane] + pb[(size_t)w * 128 + lane];
  }
  __syncthreads();
  float* dst = out + (size_t)b * PLANE + (size_t)h * 128;
  for (int c0 = 0; c0 < 128; c0 += 2) {
    const int c = c0 + half;
    dst[(size_t)c * NPOS + lane] = tile[lane][c];
  }
}

extern "C" void kernel_launch(void* const* d_in, const int* in_sizes, int n_in,
                              void* d_out, int out_size, void* d_ws, size_t ws_size,
                              hipStream_t stream) {
  const float* x = (const float*)d_in[0];
  const float* y = (const float*)d_in[1];
  const float* w1 = (const float*)d_in[2];  const float* b1 = (const float*)d_in[3];
  const float* w2 = (const float*)d_in[4];  const float* b2 = (const float*)d_in[5];
  const float* w4 = (const float*)d_in[6];  const float* b4 = (const float*)d_in[7];
  const float* w5 = (const float*)d_in[8];  const float* b5 = (const float*)d_in[9];
  const float* w7 = (const float*)d_in[10]; const float* b7 = (const float*)d_in[11];
  const float* w8 = (const float*)d_in[12]; const float* b8 = (const float*)d_in[13];
  const float* w9 = (const float*)d_in[14]; const float* b9 = (const float*)d_in[15];
  const float* w10 = (const float*)d_in[16]; const float* b10 = (const float*)d_in[17];
  const float* w12 = (const float*)d_in[18]; const float* b12 = (const float*)d_in[19];
  const float* w13 = (const float*)d_in[20]; const float* b13 = (const float*)d_in[21];
  const float* w15 = (const float*)d_in[22]; const float* b15 = (const float*)d_in[23];
  const float* w16 = (const float*)d_in[24]; const float* b16 = (const float*)d_in[25];

  if (ws_size < 167772160) return;  // 160MB
  char* ws = (char*)d_ws;
  ushort* xt_hi = (ushort*)ws;                // 0   .. 16MB
  ushort* xt_lo = (ushort*)(ws + 16777216);   // 16  .. 32MB
  float* yt1 = (float*)(ws + 33554432);       // 32  .. 64MB
  float* yt2 = (float*)(ws + 67108864);       // 64  .. 96MB
  ushort* hs_hi = (ushort*)(ws + 100663296);  // 96  .. 112MB
  ushort* hs_lo = (ushort*)(ws + 117440512);  // 112 .. 128MB
  ushort* hn_hi = (ushort*)(ws + 134217728);  // 128 .. 144MB
  ushort* hn_lo = (ushort*)(ws + 150994944);  // 144 .. 160MB
  float* outA = (float*)ws;                   // overlay xt (dead after ph1)
  float* outB = (float*)(ws + 33554432);      // overlay yt1 (dead after ph1)

  dim3 blk(256);
  k_transpose_x<<<512, blk, 0, stream>>>(x, xt_hi, xt_lo);
  k_transpose_y<<<512, blk, 0, stream>>>(y, yt1, yt2);
  k_scan_ph1<<<64, blk, 0, stream>>>(xt_hi, xt_lo, yt1, hs_hi, hs_lo, hn_hi, hn_lo,
                                     w1, b1, w2, b2, w9, b9, w10, b10);
  k_scan_ph2<<<64, blk, 0, stream>>>(hs_hi, hs_lo, hn_hi, hn_lo, yt2, outA, outB,
                                     w4, b4, w5, b5, w7, b7, w8, b8,
                                     w12, b12, w13, b13, w15, b15, w16, b16);
  k_final<<<512, blk, 0, stream>>>(outA, outB, (float*)d_out);
}

// Round 12
// 387.178 us; speedup vs baseline: 1.5220x; 1.5220x over previous
//
#include <hip/hip_runtime.h>

typedef unsigned int uint;
typedef unsigned short ushort;
typedef __attribute__((ext_vector_type(8))) short short8;  // 8 bf16 = 4 VGPR
typedef __attribute__((ext_vector_type(4))) float f32x4;

#define NPOS 16384
#define PLANE 2097152
// LDS map (bytes), fragment-linear (r7-proven, ~zero conflicts):
//   X ring : 4 slots x [hi 4KB | lo 4KB]   G ring : 4 slots x 8KB fp32
//   H dbuf : 2 x [hi 4KB | lo 4KB]         O ring : 4 slots x 8KB fp32 (MID)
#define XR_OFF 0
#define GR_OFF 32768
#define HP_OFF 65536
#define OR_OFF 81920
#define LDS_PH1 81920
#define LDS_PH2 114688

__device__ __forceinline__ uint fbits(float a) { return __builtin_bit_cast(uint, a); }
__device__ __forceinline__ uint rnehi(float a) {  // RNE bf16 high split
  const uint u = fbits(a);
  return (u + 0x7FFFu + ((u >> 16) & 1u)) & 0xFFFF0000u;
}
__device__ __forceinline__ float fhi(float a) { return __builtin_bit_cast(float, rnehi(a)); }
__device__ __forceinline__ uint packhi(float a, float b) { return (rnehi(a) >> 16) | rnehi(b); }
__device__ __forceinline__ uint packtr(float a, float b) {
  return (fbits(a) >> 16) | (fbits(b) & 0xFFFF0000u);
}
__device__ __forceinline__ float b2f(uint h16) { return __builtin_bit_cast(float, h16 << 16); }

__device__ __forceinline__ f32x4 MF(short8 a, short8 b, f32x4 c) {
  return __builtin_amdgcn_mfma_f32_16x16x32_bf16(a, b, c, 0, 0, 0);
}
__device__ __forceinline__ void fill16(const void* g, char* l) {
  __builtin_amdgcn_global_load_lds((const __attribute__((address_space(1))) void*)g,
                                   (__attribute__((address_space(3))) void*)l, 16, 0, 0);
}
__device__ __forceinline__ void split8(float4 v0, float4 v1, short8& hi, short8& lo) {
  union { short8 s; uint u[4]; } H, L;
  H.u[0] = packhi(v0.x, v0.y); H.u[1] = packhi(v0.z, v0.w);
  H.u[2] = packhi(v1.x, v1.y); H.u[3] = packhi(v1.z, v1.w);
  L.u[0] = packtr(v0.x - fhi(v0.x), v0.y - fhi(v0.y));
  L.u[1] = packtr(v0.z - fhi(v0.z), v0.w - fhi(v0.w));
  L.u[2] = packtr(v1.x - fhi(v1.x), v1.y - fhi(v1.y));
  L.u[3] = packtr(v1.z - fhi(v1.z), v1.w - fhi(v1.w));
  hi = H.s; lo = L.s;
}

#define BAR() asm volatile("s_waitcnt lgkmcnt(0)\n\ts_barrier" ::: "memory")

__global__ __launch_bounds__(256) void k_transpose_x(const float* __restrict__ x,
                                                     ushort* __restrict__ xhi,
                                                     ushort* __restrict__ xlo) {
  __shared__ float tile[128][129];
  const int b = blockIdx.x >> 7, h = blockIdx.x & 127;
  const int t = threadIdx.x, half = t >> 7, lane = t & 127;
  const float* src = x + (size_t)b * PLANE + (size_t)h * 128;  // [c][w]
  for (int c0 = 0; c0 < 128; c0 += 2) {
    const int c = c0 + half;
    tile[c][lane] = src[(size_t)c * NPOS + lane];
  }
  __syncthreads();
  const int wq = t >> 6, cp = t & 63;
  for (int w0 = 0; w0 < 128; w0 += 4) {
    const int w = w0 + wq;
    const float v0 = tile[2 * cp][w], v1 = tile[2 * cp + 1][w];
    const size_t e = ((size_t)(b * 128 + w) * 128 + h) * 128 + 2 * cp;
    *(uint*)(xhi + e) = packhi(v0, v1);
    *(uint*)(xlo + e) = packtr(v0 - fhi(v0), v1 - fhi(v1));
  }
}

__global__ __launch_bounds__(256) void k_transpose_y(const float* __restrict__ y,
                                                     float* __restrict__ yt1,
                                                     float* __restrict__ yt2) {
  __shared__ float tile[128][129];
  const int b = blockIdx.x >> 7, h = blockIdx.x & 127;
  const int t = threadIdx.x, half = t >> 7, lane = t & 127;
  const float* src = y + (size_t)b * PLANE + (size_t)h * 128;
  for (int c0 = 0; c0 < 128; c0 += 2) {
    const int c = c0 + half;
    tile[c][lane] = src[(size_t)c * NPOS + lane];
  }
  __syncthreads();
  float* d1 = yt1 + (size_t)b * PLANE + (size_t)h * 128;
  float* d2 = yt2 + ((size_t)(b * 128 + h)) * NPOS;
  for (int w0 = 0; w0 < 128; w0 += 2) {
    const int w = w0 + half;
    const float v = tile[lane][w];
    d1[(size_t)w * NPOS + lane] = v;
    d2[(size_t)w * 128 + lane] = v;
  }
}

__global__ void k_zeroflags(int* __restrict__ f) { f[threadIdx.x] = 0; }

// ---------------------------------------------------------------------------
// 16-line batched gated scan (r7 body). 4 waves; wave wv owns rows [32wv,+32).
// MID (midpoint protocol, replaces the 2-pass ACCUM):
//   fwd(REV=0) and rev(REV=1) blocks run CONCURRENTLY on one output buffer.
//   steps 0..63  : plain store h to out[P(s)] (position halves are disjoint).
//   end step 63  : vmcnt(0) per wave -> barrier -> thread0 RELEASE/AGENT flag.
//   top step 64  : spin ACQUIRE/AGENT on partner flag (publish precedes spin
//                  in program order on BOTH sides -> deadlock impossible),
//                  then burst-fill O slots for P(64..66) + one-time vmcnt(0).
//   steps 64..127: store h + partner value (RMW of partner's early half);
//                  steady-state fillO at distance 3 (identical to r7 ACCUM).
// ---------------------------------------------------------------------------
template <bool RELU0, bool REV, bool MID, bool OUT16>
__device__ __forceinline__ void scan16(
    char* lds,
    const ushort* __restrict__ xhi, const ushort* __restrict__ xlo, size_t in_base,
    const float* __restrict__ gate, size_t gate_base,
    float* __restrict__ outf, ushort* __restrict__ outhi, ushort* __restrict__ outlo,
    size_t out_base, int out_ps, int out_ls,
    const float* __restrict__ Wa, const float* __restrict__ Ba,
    const float* __restrict__ Wb, const float* __restrict__ Bb,
    int* myflag, int* pflag) {
  const int t = threadIdx.x;
  const int wv = t >> 6, l = t & 63;
  const int line = l & 15, g4 = l >> 4;

  short8 wah[2][4], wal[2][4], wbh[2][4], wbl[2][4];
#pragma unroll
  for (int tt = 0; tt < 2; ++tt)
#pragma unroll
    for (int kt = 0; kt < 4; ++kt) {
      const int row = 32 * wv + 16 * tt + line;
      const int kc = 32 * kt + 8 * g4;
      split8(*(const float4*)(Wa + row * 128 + kc), *(const float4*)(Wa + row * 128 + kc + 4),
             wah[tt][kt], wal[tt][kt]);
      split8(*(const float4*)(Wb + row * 128 + kc), *(const float4*)(Wb + row * 128 + kc + 4),
             wbh[tt][kt], wbl[tt][kt]);
    }
  f32x4 baf[2], bbf[2];
#pragma unroll
  for (int tt = 0; tt < 2; ++tt) {
    baf[tt] = *(const f32x4*)(Ba + 32 * wv + 16 * tt + 4 * g4);
    bbf[tt] = *(const f32x4*)(Bb + 32 * wv + 16 * tt + 4 * g4);
  }

  auto P = [](int p) -> int { return REV ? 127 - p : p; };

  const int sp = wv >> 1;
  const ushort* xsrc = sp ? xlo : xhi;
  const int lf = l & 15;

  auto fillX = [&](int p, int slot) {
#pragma unroll
    for (int f = 0; f < 2; ++f) {
      const int kg = 2 * (wv & 1) + f;
      const int cc = 4 * kg + (l >> 4);
      fill16(xsrc + in_base + (size_t)lf * NPOS + (size_t)p * 128 + 8 * cc,
             lds + XR_OFF + slot * 8192 + sp * 4096 + kg * 1024 + l * 16);
    }
  };
  auto fillG = [&](int p, int slot) {
#pragma unroll
    for (int f = 0; f < 2; ++f)
      fill16(gate + gate_base + (size_t)lf * NPOS + (size_t)p * 128 + 32 * wv + 16 * f + 4 * (l >> 4),
             lds + GR_OFF + slot * 8192 + wv * 2048 + f * 1024 + l * 16);
  };
  auto fillO = [&](int p, int slot) {
#pragma unroll
    for (int f = 0; f < 2; ++f)
      fill16(outf + out_base + (size_t)p * out_ps + (size_t)lf * out_ls + 32 * wv + 16 * f + 4 * (l >> 4),
             lds + OR_OFF + slot * 8192 + wv * 2048 + f * 1024 + l * 16);
  };

  // prologue: X slots 0..3, G slots 0..2 (no O fills: first RMW is step 64)
#pragma unroll
  for (int p = 0; p < 4; ++p) {
    fillX(P(p), p);
    if (p < 3) fillG(P(p), p);
  }
  asm volatile("s_waitcnt vmcnt(0) lgkmcnt(0)\n\ts_barrier" ::: "memory");

  // ---- step 0: h0 = relu?(x[P(0)]) ----
  {
    char* Hwr = lds + HP_OFF;
#pragma unroll
    for (int tt = 0; tt < 2; ++tt) {
      const int cw = 4 * wv + 2 * tt + (g4 >> 1);
      const int boff = (cw * 16 + line) * 16 + 8 * (g4 & 1);
      const uint2 xh = *(const uint2*)(lds + XR_OFF + boff);
      const uint2 xl = *(const uint2*)(lds + XR_OFF + 4096 + boff);
      float4 f;
      f.x = b2f(xh.x & 0xFFFFu) + b2f(xl.x & 0xFFFFu);
      f.y = b2f(xh.x >> 16) + b2f(xl.x >> 16);
      f.z = b2f(xh.y & 0xFFFFu) + b2f(xl.y & 0xFFFFu);
      f.w = b2f(xh.y >> 16) + b2f(xl.y >> 16);
      if (RELU0) {
        f.x = fmaxf(f.x, 0.f); f.y = fmaxf(f.y, 0.f);
        f.z = fmaxf(f.z, 0.f); f.w = fmaxf(f.w, 0.f);
      }
      uint2 hw, lw;
      hw.x = packhi(f.x, f.y); hw.y = packhi(f.z, f.w);
      lw.x = packtr(f.x - fhi(f.x), f.y - fhi(f.y));
      lw.y = packtr(f.z - fhi(f.z), f.w - fhi(f.w));
      *(uint2*)(Hwr + boff) = hw;
      *(uint2*)(Hwr + 4096 + boff) = lw;
      const int ci0 = 32 * wv + 16 * tt + 4 * g4;
      const size_t oe = out_base + (size_t)P(0) * out_ps + (size_t)line * out_ls + ci0;
      if (OUT16) {
        *(uint2*)(outhi + oe) = hw;
        *(uint2*)(outlo + oe) = lw;
      } else {
        *(float4*)(outf + oe) = f;  // step 0 is first-half: plain store
      }
    }
  }
  BAR();

  // ---- main loop ----
#pragma unroll 1
  for (int s = 1; s < 128; ++s) {
    if (MID && s == 64) {
      // partner flag was published at the end of OUR step 63 too (program
      // order: publish THEN spin on both sides -> no deadlock).
      while (__hip_atomic_load(pflag, __ATOMIC_ACQUIRE, __HIP_MEMORY_SCOPE_AGENT) == 0)
        __builtin_amdgcn_s_sleep(2);
      fillO(P(64), 0);
      fillO(P(65), 1);
      fillO(P(66), 2);
    }
    if (s <= 124) {
      fillX(P(s + 3), (s + 3) & 3);
      fillG(P(s + 2), (s + 2) & 3);
      if (MID && s >= 64) fillO(P(s + 3), (s + 3) & 3);
    }
    if (MID && s == 64)  // one-time drain: O slot 0 ready for this epilogue
      asm volatile("s_waitcnt vmcnt(0)" ::: "memory");

    f32x4 aF0 = baf[0], aF1 = baf[1], aR0 = bbf[0], aR1 = bbf[1];
    const char* H = lds + HP_OFF + ((s - 1) & 1) * 8192;
    const char* X = lds + XR_OFF + (s & 3) * 8192;
    __builtin_amdgcn_s_setprio(1);
#pragma unroll
    for (int kt = 0; kt < 4; ++kt) {
      const short8 hh = *(const short8*)(H + kt * 1024 + l * 16);
      const short8 hl = *(const short8*)(H + 4096 + kt * 1024 + l * 16);
      const short8 xh = *(const short8*)(X + kt * 1024 + l * 16);
      const short8 xl = *(const short8*)(X + 4096 + kt * 1024 + l * 16);
      aR0 = MF(wbh[0][kt], hh, aR0);
      aR1 = MF(wbh[1][kt], hh, aR1);
      aF0 = MF(wah[0][kt], xh, aF0);
      aF1 = MF(wah[1][kt], xh, aF1);
      aR0 = MF(wbh[0][kt], hl, aR0);
      aR1 = MF(wbh[1][kt], hl, aR1);
      aF0 = MF(wah[0][kt], xl, aF0);
      aF1 = MF(wah[1][kt], xl, aF1);
      aR0 = MF(wbl[0][kt], hh, aR0);
      aR1 = MF(wbl[1][kt], hh, aR1);
      aF0 = MF(wal[0][kt], xh, aF0);
      aF1 = MF(wal[1][kt], xh, aF1);
    }
    __builtin_amdgcn_s_setprio(0);

    const char* Grd = lds + GR_OFF + ((s - 1) & 3) * 8192 + wv * 2048;
    const char* Ord = lds + OR_OFF + (s & 3) * 8192 + wv * 2048;
    char* Hwr = lds + HP_OFF + (s & 1) * 8192;
    const f32x4 aR[2] = {aR0, aR1}, aF[2] = {aF0, aF1};
#pragma unroll
    for (int tt = 0; tt < 2; ++tt) {
      const f32x4 g = *(const f32x4*)(Grd + tt * 1024 + l * 16);
      float4 h;
      h.x = fmaxf(fmaf(aR[tt][0], g[0], aF[tt][0]), 0.f);
      h.y = fmaxf(fmaf(aR[tt][1], g[1], aF[tt][1]), 0.f);
      h.z = fmaxf(fmaf(aR[tt][2], g[2], aF[tt][2]), 0.f);
      h.w = fmaxf(fmaf(aR[tt][3], g[3], aF[tt][3]), 0.f);
      uint2 hw, lw;
      hw.x = packhi(h.x, h.y); hw.y = packhi(h.z, h.w);
      lw.x = packtr(h.x - fhi(h.x), h.y - fhi(h.y));
      lw.y = packtr(h.z - fhi(h.z), h.w - fhi(h.w));
      const int cw = 4 * wv + 2 * tt + (g4 >> 1);
      const int boff = (cw * 16 + line) * 16 + 8 * (g4 & 1);
      *(uint2*)(Hwr + boff) = hw;
      *(uint2*)(Hwr + 4096 + boff) = lw;
      const int ci0 = 32 * wv + 16 * tt + 4 * g4;
      const size_t oe = out_base + (size_t)P(s) * out_ps + (size_t)line * out_ls + ci0;
      if (OUT16) {
        *(uint2*)(outhi + oe) = hw;
        *(uint2*)(outlo + oe) = lw;
      } else {
        float4 o = h;
        if (MID && s >= 64) {  // second half: add partner's early value
          const f32x4 ov = *(const f32x4*)(Ord + tt * 1024 + l * 16);
          o.x += ov[0]; o.y += ov[1]; o.z += ov[2]; o.w += ov[3];
        }
        *(float4*)(outf + oe) = o;
      }
    }
    if constexpr (MID)
      asm volatile("s_waitcnt vmcnt(16)" ::: "memory");
    else if constexpr (OUT16)
      asm volatile("s_waitcnt vmcnt(18)" ::: "memory");
    else
      asm volatile("s_waitcnt vmcnt(12)" ::: "memory");
    BAR();
    if (MID && s == 63) {
      // publish our first half: drain own stores, sync all waves, release flag
      asm volatile("s_waitcnt vmcnt(0)" ::: "memory");
      __builtin_amdgcn_s_barrier();
      if (threadIdx.x == 0)
        __hip_atomic_store(myflag, 1, __ATOMIC_RELEASE, __HIP_MEMORY_SCOPE_AGENT);
    }
  }
}

// Phase 1: 64 blocks = [scan(2)][b(4)][wgrp(8)]
__global__ __launch_bounds__(256, 1) void k_scan_ph1(
    const ushort* __restrict__ xhi, const ushort* __restrict__ xlo,
    const float* __restrict__ yt1,
    ushort* __restrict__ hs_hi, ushort* __restrict__ hs_lo,
    ushort* __restrict__ hn_hi, ushort* __restrict__ hn_lo,
    const float* w1, const float* b1, const float* w2, const float* b2,
    const float* w9, const float* b9, const float* w10, const float* b10) {
  __shared__ __align__(16) char lds[LDS_PH1];
  const int id = blockIdx.x;
  const int scan = id >> 5, b = (id >> 3) & 3, wg = id & 7;
  const size_t in_base = ((size_t)(b * 128 + wg * 16)) * NPOS;
  const size_t out_base = (size_t)b * PLANE + (size_t)(wg * 16) * 128;
  if (scan == 0)
    scan16<false, false, false, true>(lds, xhi, xlo, in_base, yt1, in_base,
                                      nullptr, hs_hi, hs_lo, out_base, NPOS, 128,
                                      w1, b1, w2, b2, nullptr, nullptr);
  else
    scan16<true, true, false, true>(lds, xhi, xlo, in_base, yt1, in_base,
                                    nullptr, hn_hi, hn_lo, out_base, NPOS, 128,
                                    w9, b9, w10, b10, nullptr, nullptr);
}

// Phase 2: 128 blocks = [rev(2)][grp(2)][b(4)][hg(8)] -- fwd and rev of each
// direction-pair run CONCURRENTLY on the shared buffer via midpoint protocol.
__global__ __launch_bounds__(256, 1) void k_scan_ph2(
    const ushort* __restrict__ hs_hi, const ushort* __restrict__ hs_lo,
    const ushort* __restrict__ hn_hi, const ushort* __restrict__ hn_lo,
    const float* __restrict__ yt2, float* __restrict__ outA, float* __restrict__ outB,
    int* __restrict__ flags,
    const float* w4, const float* b4, const float* w5, const float* b5,
    const float* w7, const float* b7, const float* w8, const float* b8,
    const float* w12, const float* b12, const float* w13, const float* b13,
    const float* w15, const float* b15, const float* w16, const float* b16) {
  __shared__ __align__(16) char lds[LDS_PH2];
  const int id = blockIdx.x;
  const int rev = id >> 6, rest = id & 63;
  const int grp = rest >> 5, b = (rest >> 3) & 3, hg = rest & 7;
  const size_t base = ((size_t)(b * 128 + hg * 16)) * NPOS;
  const ushort* ihi = grp ? hn_hi : hs_hi;
  const ushort* ilo = grp ? hn_lo : hs_lo;
  float* o = grp ? outB : outA;
  int* myf = flags + rest * 2 + rev;
  int* pf = flags + rest * 2 + (rev ^ 1);
  const float* wa; const float* ba; const float* wb; const float* bb;
  if (grp == 0) {
    wa = rev ? w7 : w4;  ba = rev ? b7 : b4;
    wb = rev ? w8 : w5;  bb = rev ? b8 : b5;
  } else {
    wa = rev ? w15 : w12; ba = rev ? b15 : b12;
    wb = rev ? w16 : w13; bb = rev ? b16 : b13;
  }
  // out element [pos=w][line=h][c]: pos stride 128, line stride NPOS
  if (rev)
    scan16<true, true, true, false>(lds, ihi, ilo, base, yt2, base,
                                    o, nullptr, nullptr, base, 128, NPOS,
                                    wa, ba, wb, bb, myf, pf);
  else
    scan16<true, false, true, false>(lds, ihi, ilo, base, yt2, base,
                                     o, nullptr, nullptr, base, 128, NPOS,
                                     wa, ba, wb, bb, myf, pf);
}

// out[b][c][h][w] = outA[b][h][w][c] + outB[b][h][w][c]
__global__ __launch_bounds__(256) void k_final(const float* __restrict__ outA,
                                               const float* __restrict__ outB,
                                               float* __restrict__ out) {
  __shared__ float tile[128][129];
  const int b = blockIdx.x >> 7, h = blockIdx.x & 127;
  const int t = threadIdx.x, half = t >> 7, lane = t & 127;
  const float* pa = outA + ((size_t)(b * 128 + h)) * NPOS;
  const float* pb = outB + ((size_t)(b * 128 + h)) * NPOS;
  for (int w0 = 0; w0 < 128; w0 += 2) {
    const int w = w0 + half;
    tile[w][lane] = pa[(size_t)w * 128 + lane] + pb[(size_t)w * 128 + lane];
  }
  __syncthreads();
  float* dst = out + (size_t)b * PLANE + (size_t)h * 128;
  for (int c0 = 0; c0 < 128; c0 += 2) {
    const int c = c0 + half;
    dst[(size_t)c * NPOS + lane] = tile[lane][c];
  }
}

extern "C" void kernel_launch(void* const* d_in, const int* in_sizes, int n_in,
                              void* d_out, int out_size, void* d_ws, size_t ws_size,
                              hipStream_t stream) {
  const float* x = (const float*)d_in[0];
  const float* y = (const float*)d_in[1];
  const float* w1 = (const float*)d_in[2];  const float* b1 = (const float*)d_in[3];
  const float* w2 = (const float*)d_in[4];  const float* b2 = (const float*)d_in[5];
  const float* w4 = (const float*)d_in[6];  const float* b4 = (const float*)d_in[7];
  const float* w5 = (const float*)d_in[8];  const float* b5 = (const float*)d_in[9];
  const float* w7 = (const float*)d_in[10]; const float* b7 = (const float*)d_in[11];
  const float* w8 = (const float*)d_in[12]; const float* b8 = (const float*)d_in[13];
  const float* w9 = (const float*)d_in[14]; const float* b9 = (const float*)d_in[15];
  const float* w10 = (const float*)d_in[16]; const float* b10 = (const float*)d_in[17];
  const float* w12 = (const float*)d_in[18]; const float* b12 = (const float*)d_in[19];
  const float* w13 = (const float*)d_in[20]; const float* b13 = (const float*)d_in[21];
  const float* w15 = (const float*)d_in[22]; const float* b15 = (const float*)d_in[23];
  const float* w16 = (const float*)d_in[24]; const float* b16 = (const float*)d_in[25];

  if (ws_size < 167772160) return;  // 160MB
  char* ws = (char*)d_ws;
  ushort* xt_hi = (ushort*)ws;                // 0   .. 16MB
  ushort* xt_lo = (ushort*)(ws + 16777216);   // 16  .. 32MB
  float* yt1 = (float*)(ws + 33554432);       // 32  .. 64MB
  float* yt2 = (float*)(ws + 67108864);       // 64  .. 96MB
  ushort* hs_hi = (ushort*)(ws + 100663296);  // 96  .. 112MB
  ushort* hs_lo = (ushort*)(ws + 117440512);  // 112 .. 128MB
  ushort* hn_hi = (ushort*)(ws + 134217728);  // 128 .. 144MB
  ushort* hn_lo = (ushort*)(ws + 150994944);  // 144 .. 160MB
  float* outA = (float*)ws;                   // overlay xt (dead after ph1)
  float* outB = (float*)(ws + 33554432);      // overlay yt1 (dead after ph1)
  int* flags = (int*)d_out;                   // 128 ints; k_final overwrites later

  dim3 blk(256);
  k_transpose_x<<<512, blk, 0, stream>>>(x, xt_hi, xt_lo);
  k_transpose_y<<<512, blk, 0, stream>>>(y, yt1, yt2);
  k_zeroflags<<<1, 128, 0, stream>>>(flags);
  k_scan_ph1<<<64, blk, 0, stream>>>(xt_hi, xt_lo, yt1, hs_hi, hs_lo, hn_hi, hn_lo,
                                     w1, b1, w2, b2, w9, b9, w10, b10);
  k_scan_ph2<<<128, blk, 0, stream>>>(hs_hi, hs_lo, hn_hi, hn_lo, yt2, outA, outB, flags,
                                      w4, b4, w5, b5, w7, b7, w8, b8,
                                      w12, b12, w13, b13, w15, b15, w16, b16);
  k_final<<<512, blk, 0, stream>>>(outA, outB, (float*)d_out);
}